// Round 2
// 1952.876 us; speedup vs baseline: 1.3019x; 1.3019x over previous
//
#include <hip/hip_runtime.h>
#include <hip/hip_fp16.h>

// Masked LSTM, T=512 B=64 D=512 H=512.
// Phase A: x_proj = inputs @ W_ih^T + (b_ih + b_hh), fp16 MFMA GEMM (fp32 accum),
//          reg-staged fp32->fp16 conversion inline, 128x128 tile, BK=64, 4 waves.
//          Output stored as fp16 (halves write traffic; quantum ~2^-10 rel).
// Phase B: persistent recurrence, fp16 MFMA 16x16x32 (was bf16 — fp16 is 8x more
//          precise at these magnitudes, same speed/layout). 8 groups x 32 blocks;
//          group owns 8 batches (padded to M=16), block owns 16 h-dims = 64 gate
//          rows. W_hh fp16 resident in LDS (stride 520 -> max 2-way aliasing =
//          free). h exchanged as fp16 via L3 with RELAXED AGENT-scope atomics.
//          8 waves = 4 gate tiles x 2 k-splits; 2-way LDS reduce; 128-thr epilogue.

#define T_DIM 512
#define B_DIM 64
#define D_DIM 512
#define H_DIM 512
#define G_DIM 2048
#define M_DIM (T_DIM * B_DIM)

#define NGROUP 8
#define BPG 32
#define NBLK (NGROUP * BPG)     // 256
#define NTHR 512
#define JPB 16                  // h-dims per block
#define BPGRP 8                 // batches per group
#define WS 520                  // LDS row stride in fp16 elements (512 + 8 pad)

typedef __attribute__((ext_vector_type(8))) _Float16 half8;
typedef __attribute__((ext_vector_type(2))) __fp16 fp16x2;
typedef __attribute__((ext_vector_type(4))) float float4v;

#define AT_LD_U(p)    __hip_atomic_load((p), __ATOMIC_RELAXED, __HIP_MEMORY_SCOPE_AGENT)
#define AT_ST_U(p, v) __hip_atomic_store((p), (v), __ATOMIC_RELAXED, __HIP_MEMORY_SCOPE_AGENT)
#define AT_LD_I(p)    __hip_atomic_load((p), __ATOMIC_RELAXED, __HIP_MEMORY_SCOPE_AGENT)
#define AT_ST_I(p, v) __hip_atomic_store((p), (v), __ATOMIC_RELAXED, __HIP_MEMORY_SCOPE_AGENT)

__device__ __forceinline__ float sigf(float x) { return 1.0f / (1.0f + __expf(-x)); }
__device__ __forceinline__ float tanhfast(float x) { return 2.0f / (1.0f + __expf(-2.0f * x)) - 1.0f; }
__device__ __forceinline__ unsigned short f2h(float x) {
  return __builtin_bit_cast(unsigned short, (_Float16)x);   // RNE v_cvt_f16_f32
}
__device__ __forceinline__ unsigned pk2h(float a, float b) {
  fp16x2 h = __builtin_amdgcn_cvt_pkrtz(a, b);              // packed RTZ
  return __builtin_bit_cast(unsigned, h);
}

// ---------------------------------------------------------------- Phase A (fp16 MFMA)
// C[m][g] = sum_d A[m][d] * W[g][d] + bias[g].  Both operands K-contiguous.
// Grid 4096 = 256 m-tiles x 16 n-tiles; swizzle groups all 16 n-tiles of an m-tile
// onto one XCD consecutively so the fp32 A-tile (256KB) stays L2-resident.
__global__ __launch_bounds__(256) void xproj_mfma(
    const float* __restrict__ A, const float* __restrict__ W,
    const float* __restrict__ b1, const float* __restrict__ b2,
    __half* __restrict__ C) {
  __shared__ __align__(16) _Float16 As[128 * 72];   // stride 72 f16 = 144B (16-aligned, +8 pad)
  __shared__ __align__(16) _Float16 Bs[128 * 72];
  const int tid = threadIdx.x;
  const int bid = blockIdx.x;
  const int xcd = bid & 7, idx = bid >> 3;
  const int mt = xcd * 32 + (idx >> 4);   // 0..255
  const int nt = idx & 15;                // 0..15
  const int lane = tid & 63;
  const int w = tid >> 6;
  const int wm = w >> 1, wn = w & 1;      // wave quadrant (64x64)
  const int fr = lane & 15;               // fragment row
  const int ko = (lane >> 4) * 8;         // k-octet within 32
  const int srow = tid >> 4, sf4 = tid & 15;

  const float* Ab = A + (size_t)(mt * 128) * D_DIM;
  const float* Wb = W + (size_t)(nt * 128) * D_DIM;

  float4v acc[4][4];
#pragma unroll
  for (int m = 0; m < 4; ++m)
#pragma unroll
    for (int n = 0; n < 4; ++n) acc[m][n] = (float4v){0.f, 0.f, 0.f, 0.f};

  for (int k0 = 0; k0 < D_DIM; k0 += 64) {
    float4 aR[8], wR[8];
#pragma unroll
    for (int i = 0; i < 8; ++i) {
      aR[i] = *(const float4*)(Ab + (size_t)(srow + i * 16) * D_DIM + k0 + sf4 * 4);
      wR[i] = *(const float4*)(Wb + (size_t)(srow + i * 16) * D_DIM + k0 + sf4 * 4);
    }
    __syncthreads();   // previous iter's LDS reads done
#pragma unroll
    for (int i = 0; i < 8; ++i) {
      int row = srow + i * 16;
      *(uint2*)(As + row * 72 + sf4 * 4) =
          make_uint2(pk2h(aR[i].x, aR[i].y), pk2h(aR[i].z, aR[i].w));
      *(uint2*)(Bs + row * 72 + sf4 * 4) =
          make_uint2(pk2h(wR[i].x, wR[i].y), pk2h(wR[i].z, wR[i].w));
    }
    __syncthreads();
#pragma unroll
    for (int kk = 0; kk < 2; ++kk) {
      half8 af[4], bf[4];
#pragma unroll
      for (int m = 0; m < 4; ++m)
        af[m] = *(const half8*)(As + (wm * 64 + m * 16 + fr) * 72 + kk * 32 + ko);
#pragma unroll
      for (int n = 0; n < 4; ++n)
        bf[n] = *(const half8*)(Bs + (wn * 64 + n * 16 + fr) * 72 + kk * 32 + ko);
#pragma unroll
      for (int m = 0; m < 4; ++m)
#pragma unroll
        for (int n = 0; n < 4; ++n)
          acc[m][n] = __builtin_amdgcn_mfma_f32_16x16x32_f16(af[m], bf[n], acc[m][n], 0, 0, 0);
    }
  }
  // epilogue: bias + fp16 store. D row=(lane>>4)*4+reg, col=lane&15 (dtype-indep mapping)
#pragma unroll
  for (int n = 0; n < 4; ++n) {
    int gcol = nt * 128 + wn * 64 + n * 16 + fr;
    float bias = b1[gcol] + b2[gcol];
#pragma unroll
    for (int m = 0; m < 4; ++m) {
      size_t grow = (size_t)(mt * 128 + wm * 64 + m * 16 + (lane >> 4) * 4);
      __half* cp = C + grow * G_DIM + gcol;
#pragma unroll
      for (int r = 0; r < 4; ++r)
        cp[(size_t)r * G_DIM] = (__half)(acc[m][n][r] + bias);
    }
  }
}

// ---------------------------------------------------------------- group barrier
__device__ __forceinline__ void gbarrier(int* slots, int rank, int target) {
  __syncthreads();   // drains vmcnt(0): this block's sc1 stores are at the coherence point
  const int tid = threadIdx.x;
  if (tid == 0) AT_ST_I(&slots[rank], target);
  if (tid < 64) {
    int v;
    do {
      v = (tid < BPG) ? AT_LD_I(&slots[tid]) : target;
      if (__all(v >= target)) break;
      __builtin_amdgcn_s_sleep(2);
    } while (true);
  }
  __syncthreads();
  __asm__ volatile("" ::: "memory");
}

// ---------------------------------------------------------------- Phase B (MFMA)
__global__ __launch_bounds__(NTHR) void lstm_seq(
    const __half* __restrict__ xproj, const float* __restrict__ mask,
    const float* __restrict__ h0, const float* __restrict__ Whh,
    float* __restrict__ out, unsigned short* __restrict__ hbuf,
    int* slot_base) {
  extern __shared__ char smemc[];
  unsigned short* Wl = (unsigned short*)smemc;     // [r][k] 64 x WS f16 = 66560 B
  unsigned short* hl = Wl + 64 * WS;               // [m][k] 16 x WS f16 = 16640 B (m>=8 garbage)
  float* part = (float*)(hl + 16 * WS);            // 8 waves x 256 f32 = 8192 B
  float* gl = part + 2048;                         // [b][r] 8 x 64 f32 = 2048 B
  float* cl = gl + 512;                            // 128 f32

  const int tid = threadIdx.x;
  const int blk = blockIdx.x;
  const int grp = blk & 7;
  const int rank = blk >> 3;
  const int bbase = grp * BPGRP;
  const int jbase = rank * JPB;
  int* slots = (int*)((char*)slot_base + grp * 128);

  // W_hh slice -> LDS fp16. r = q*16 + jl <-> global row q*512 + jbase + jl.
  for (int idx = tid; idx < 64 * 128; idx += NTHR) {
    int r = idx >> 7;
    int k4 = (idx & 127) << 2;
    int grow = (r >> 4) * H_DIM + jbase + (r & 15);
    float4 wv = *(const float4*)(Whh + (size_t)grow * H_DIM + k4);
    *(uint2*)(Wl + r * WS + k4) = make_uint2(pk2h(wv.x, wv.y), pk2h(wv.z, wv.w));
  }

  const int eb = tid >> 4, ejl = tid & 15;   // tid<128: (batch 0..7, h-dim 0..15)
  float h0v = 0.0f, c0v = 0.0f;
  if (tid < 128) {
    int bglob = bbase + eb;
    int jglob = jbase + ejl;
    h0v = h0[bglob * H_DIM + jglob];
    c0v = h0v;
    cl[tid] = c0v;
  }
  // publish h0 as fp16 into buffer 0 (pack pairs via shfl; waves 0,1 fully active)
  {
    int mybits = (tid < 128) ? (int)f2h(h0v) : 0;
    int nb = __shfl_down(mybits, 1, 64);
    if (tid < 128 && ((ejl & 1) == 0)) {
      unsigned pk = (unsigned)mybits | ((unsigned)nb << 16);
      AT_ST_U((unsigned*)hbuf + (bbase + eb) * 256 + ((jbase + ejl) >> 1), pk);
    }
  }
  gbarrier(slots, rank, 1);

  const int w = tid >> 6;        // wave id
  const int lane = tid & 63;
  const int q = w & 3;           // gate tile (i,f,g,o)
  const int ks = w >> 2;         // k-split 0..1 (256 k each)
  const int am = lane & 15;      // A row (batch, padded to 16)
  const int koct = (lane >> 4) * 8;
  const int br = q * 16 + (lane & 15);   // W row in LDS

  for (int ts = 0; ts < T_DIM; ++ts) {
    const unsigned* cur32 = (const unsigned*)(hbuf + (ts & 1) * (B_DIM * H_DIM));
    unsigned* nxt32 = (unsigned*)(hbuf + ((ts + 1) & 1) * (B_DIM * H_DIM));

    // stage h (8 batches x 512 f16 = 8KB) from L3 into LDS [m][k]
#pragma unroll
    for (int i = 0; i < 4; ++i) {
      int idx = tid + i * NTHR;
      int b = idx >> 8;          // 0..7
      int ku = idx & 255;        // uint (=2 f16) index within row
      unsigned u = AT_LD_U((unsigned*)&cur32[(bbase + b) * 256 + ku]);
      ((unsigned*)hl)[b * (WS / 2) + ku] = u;
    }
    // x_proj + mask prefetch (consumed in epilogue, well overlapped)
    float xpv0 = 0.f, xpv1 = 0.f, xpv2 = 0.f, xpv3 = 0.f, mval = 1.f;
    if (tid < 128) {
      int bglob = bbase + eb;
      const __half* xb = xproj + ((size_t)ts * B_DIM + bglob) * G_DIM + jbase + ejl;
      xpv0 = (float)xb[0];
      xpv1 = (float)xb[512];
      xpv2 = (float)xb[1024];
      xpv3 = (float)xb[1536];
      mval = mask[ts * B_DIM + bglob];
    }
    __syncthreads();

    // MFMA: D[m][n] = sum_k h[m][k] * W[q*16+n][k] over this wave's 256-k slice
    float4v acc = {0.f, 0.f, 0.f, 0.f};
#pragma unroll
    for (int kc = 0; kc < 8; ++kc) {
      int k = ks * 256 + kc * 32 + koct;
      half8 a = *(const half8*)(hl + am * WS + k);
      half8 b8 = *(const half8*)(Wl + br * WS + k);
      acc = __builtin_amdgcn_mfma_f32_16x16x32_f16(a, b8, acc, 0, 0, 0);
    }
    // partials -> LDS (part doesn't alias hl): part[w][m][n]
#pragma unroll
    for (int reg = 0; reg < 4; ++reg) {
      int m = (lane >> 4) * 4 + reg;
      part[w * 256 + m * 16 + (lane & 15)] = acc[reg];
    }
    __syncthreads();
    // reduce the 2 k-splits -> gl[b][r]; only b<8 matter
    {
      int q2 = tid >> 7, m2 = (tid >> 4) & 7, n2 = tid & 15;
      float s = part[q2 * 256 + m2 * 16 + n2] + part[(q2 + 4) * 256 + m2 * 16 + n2];
      gl[m2 * 64 + q2 * 16 + n2] = s;
    }
    __syncthreads();

    float h_new = 0.f;
    if (tid < 128) {
      float iv = sigf(gl[eb * 64 + ejl] + xpv0);
      float fv = sigf(gl[eb * 64 + 16 + ejl] + xpv1);
      float gv = tanhfast(gl[eb * 64 + 32 + ejl] + xpv2);
      float ov = sigf(gl[eb * 64 + 48 + ejl] + xpv3);
      float c_old = cl[tid];
      float c_new = fv * c_old + iv * gv;
      h_new = ov * tanhfast(c_new);
      h_new = h_new * mval + h0v * (1.0f - mval);
      c_new = c_new * mval + c0v * (1.0f - mval);
      cl[tid] = c_new;
      int bglob = bbase + eb;
      int jglob = jbase + ejl;
      out[((size_t)ts * B_DIM + bglob) * H_DIM + jglob] = h_new;
      if (ts == T_DIM - 1) {
        out[(size_t)T_DIM * B_DIM * H_DIM + bglob * H_DIM + jglob] = h_new;
        out[(size_t)T_DIM * B_DIM * H_DIM + B_DIM * H_DIM + bglob * H_DIM + jglob] = c_new;
      }
    }
    // publish h_new as packed fp16 pairs (even-jl lanes store a uint)
    {
      int mybits = (tid < 128) ? (int)f2h(h_new) : 0;
      int nb = __shfl_down(mybits, 1, 64);
      if (tid < 128 && ((ejl & 1) == 0)) {
        unsigned pk = (unsigned)mybits | ((unsigned)nb << 16);
        AT_ST_U(&nxt32[(bbase + eb) * 256 + ((jbase + ejl) >> 1)], pk);
      }
    }
    gbarrier(slots, rank, ts + 2);
  }
}

// ---------------------------------------------------------------- launch
extern "C" void kernel_launch(void* const* d_in, const int* in_sizes, int n_in,
                              void* d_out, int out_size, void* d_ws, size_t ws_size,
                              hipStream_t stream) {
  const float* inputs = (const float*)d_in[0];
  const float* maskp  = (const float*)d_in[1];
  const float* h0     = (const float*)d_in[2];
  const float* W_ih   = (const float*)d_in[3];
  const float* W_hh   = (const float*)d_in[4];
  const float* b_ih   = (const float*)d_in[5];
  const float* b_hh   = (const float*)d_in[6];
  float* out = (float*)d_out;

  char* ws = (char*)d_ws;
  int* slot_base = (int*)ws;                            // 8 groups x 32 slots (128B apart)
  unsigned short* hbuf = (unsigned short*)(ws + 4096);  // fp16 h double buffer, 128KB
  __half* xp = (__half*)(ws + 4096 + 2 * (size_t)B_DIM * H_DIM * sizeof(unsigned short));

  (void)hipMemsetAsync(d_ws, 0, 4096, stream);

  size_t ldsB = (size_t)(64 * WS * 2 + 16 * WS * 2 + 2048 * 4 + 512 * 4 + 128 * 4);  // 93952 B

  xproj_mfma<<<dim3((M_DIM / 128) * (G_DIM / 128)), 256, 0, stream>>>(
      inputs, W_ih, b_ih, b_hh, xp);
  lstm_seq<<<NBLK, NTHR, ldsB, stream>>>(xp, maskp, h0, W_hh, out, hbuf, slot_base);

  (void)in_sizes; (void)n_in; (void)out_size; (void)ws_size;
}